// Round 1
// baseline (1153.249 us; speedup 1.0000x reference)
//
#include <hip/hip_runtime.h>
#include <hip/hip_bf16.h>
#include <math.h>

// Problem constants (from reference)
#define BATCH 64
#define TDIM 512
#define FEAT 2048
#define HID 1024
#define KDIM 512

// ---------------------------------------------------------------------------
// k1: Whb[b,k] = sum_h hidden[b,h] * W[k,h] + bias[k]
// grid (KDIM/4, BATCH), block 256 (4 waves); wave w computes one output.
// ---------------------------------------------------------------------------
__global__ __launch_bounds__(256) void k1_whb(const float* __restrict__ hidden,
                                              const float* __restrict__ W,
                                              const float* __restrict__ bias,
                                              float* __restrict__ whb) {
    int b = blockIdx.y;
    int k = blockIdx.x * 4 + (threadIdx.x >> 6);
    int lane = threadIdx.x & 63;
    const float* hrow = hidden + (size_t)b * HID;
    const float* wrow = W + (size_t)k * HID;
    float acc = 0.f;
    #pragma unroll 4
    for (int h = lane; h < HID; h += 64) acc += hrow[h] * wrow[h];
    #pragma unroll
    for (int off = 32; off > 0; off >>= 1) acc += __shfl_down(acc, off, 64);
    if (lane == 0) whb[b * KDIM + k] = acc + bias[k];
}

// ---------------------------------------------------------------------------
// k2: fused GEMM + tanh + dot(w) partial-energy
//   S[m][n] = sum_f feats[m][f] * U[n][f]   (m = b*T+t flat row, n = k)
//   partial[c][m] = sum_{n in 128-chunk c} tanhf(S + Whb[b][n]) * w[n]
// 128x128 tile, 256 threads, 8x8 micro-tile, BF=16 LDS staging.
// grid (M/128 = 256, KDIM/128 = 4)
// ---------------------------------------------------------------------------
#define BM 128
#define BN 128
#define BF 16
#define LDSPAD 4

__global__ __launch_bounds__(256) void k2_energy(const float* __restrict__ feats,
                                                 const float* __restrict__ U,
                                                 const float* __restrict__ whb,
                                                 const float* __restrict__ wvec,
                                                 float* __restrict__ partial) {
    __shared__ __align__(16) float As[BF][BM + LDSPAD];
    __shared__ __align__(16) float Us[BF][BN + LDSPAD];

    const int row0 = blockIdx.x * BM;   // flat bt row base (aligned: one b per block)
    const int k0   = blockIdx.y * BN;
    const int tid  = threadIdx.x;
    const int tx   = tid & 15;          // n-direction (8 cols each)
    const int ty   = tid >> 4;          // m-direction (8 rows each)

    float acc[8][8];
    #pragma unroll
    for (int i = 0; i < 8; ++i)
        #pragma unroll
        for (int j = 0; j < 8; ++j) acc[i][j] = 0.f;

    for (int f0 = 0; f0 < FEAT; f0 += BF) {
        // Stage tiles: 128 rows x 16 f each; 512 float4 loads per matrix,
        // 2 per thread. Store transposed As[kf][row].
        #pragma unroll
        for (int l = 0; l < 2; ++l) {
            int li = tid + l * 256;       // 0..511
            int r  = li >> 2;             // 0..127
            int c4 = (li & 3) * 4;        // 0,4,8,12
            float4 av = *(const float4*)(feats + (size_t)(row0 + r) * FEAT + f0 + c4);
            float4 uv = *(const float4*)(U     + (size_t)(k0   + r) * FEAT + f0 + c4);
            As[c4 + 0][r] = av.x; As[c4 + 1][r] = av.y;
            As[c4 + 2][r] = av.z; As[c4 + 3][r] = av.w;
            Us[c4 + 0][r] = uv.x; Us[c4 + 1][r] = uv.y;
            Us[c4 + 2][r] = uv.z; Us[c4 + 3][r] = uv.w;
        }
        __syncthreads();

        #pragma unroll
        for (int kf = 0; kf < BF; ++kf) {
            float4 a0 = *(const float4*)&As[kf][ty * 8];
            float4 a1 = *(const float4*)&As[kf][ty * 8 + 4];
            float4 u0 = *(const float4*)&Us[kf][tx * 8];
            float4 u1 = *(const float4*)&Us[kf][tx * 8 + 4];
            float a[8] = {a0.x, a0.y, a0.z, a0.w, a1.x, a1.y, a1.z, a1.w};
            float u[8] = {u0.x, u0.y, u0.z, u0.w, u1.x, u1.y, u1.z, u1.w};
            #pragma unroll
            for (int i = 0; i < 8; ++i)
                #pragma unroll
                for (int j = 0; j < 8; ++j) acc[i][j] += a[i] * u[j];
        }
        __syncthreads();
    }

    // Epilogue: e = tanh(S + Whb), reduce over this block's 128 k with weight w[k]
    const int b = row0 >> 9;            // T = 512
    float psum[8];
    #pragma unroll
    for (int i = 0; i < 8; ++i) {
        float s = 0.f;
        #pragma unroll
        for (int j = 0; j < 8; ++j) {
            int k = k0 + tx * 8 + j;
            s += tanhf(acc[i][j] + whb[b * KDIM + k]) * wvec[k];
        }
        psum[i] = s;
    }
    // reduce across tx (16 lanes, contiguous in lane id)
    #pragma unroll
    for (int off = 8; off > 0; off >>= 1)
        #pragma unroll
        for (int i = 0; i < 8; ++i) psum[i] += __shfl_down(psum[i], off, 16);

    if (tx == 0) {
        int c = blockIdx.y;
        #pragma unroll
        for (int i = 0; i < 8; ++i)
            partial[c * (BATCH * TDIM) + row0 + ty * 8 + i] = psum[i];
    }
}

// ---------------------------------------------------------------------------
// k3: energies = sum of 4 partials; softmax over T per batch -> weights
// grid (BATCH), block 512 (one thread per t)
// ---------------------------------------------------------------------------
__global__ __launch_bounds__(512) void k3_softmax(const float* __restrict__ partial,
                                                  float* __restrict__ wout) {
    int b = blockIdx.x;
    int t = threadIdx.x;
    float e = 0.f;
    #pragma unroll
    for (int c = 0; c < 4; ++c) e += partial[c * (BATCH * TDIM) + b * TDIM + t];

    __shared__ float sm[512];
    sm[t] = e;
    __syncthreads();
    #pragma unroll
    for (int s = 256; s > 0; s >>= 1) {
        if (t < s) sm[t] = fmaxf(sm[t], sm[t + s]);
        __syncthreads();
    }
    float m = sm[0];
    __syncthreads();
    float ex = __expf(e - m);
    sm[t] = ex;
    __syncthreads();
    #pragma unroll
    for (int s = 256; s > 0; s >>= 1) {
        if (t < s) sm[t] += sm[t + s];
        __syncthreads();
    }
    float inv = 1.f / sm[0];
    wout[b * TDIM + t] = ex * inv;
}

// ---------------------------------------------------------------------------
// k4: attn_feats[b,f] = sum_t feats[b,t,f] * weights[b,t]
// grid (FEAT/256, BATCH), block 256; weights staged in LDS.
// ---------------------------------------------------------------------------
__global__ __launch_bounds__(256) void k4_pool(const float* __restrict__ feats,
                                               const float* __restrict__ weights,
                                               float* __restrict__ out) {
    int b = blockIdx.y;
    int f = blockIdx.x * 256 + threadIdx.x;
    __shared__ float wsm[TDIM];
    wsm[threadIdx.x]       = weights[b * TDIM + threadIdx.x];
    wsm[threadIdx.x + 256] = weights[b * TDIM + 256 + threadIdx.x];
    __syncthreads();

    const float* fp = feats + (size_t)b * TDIM * FEAT + f;
    float a0 = 0.f, a1 = 0.f, a2 = 0.f, a3 = 0.f;
    #pragma unroll 4
    for (int t = 0; t < TDIM; t += 4) {
        a0 += fp[(size_t)(t + 0) * FEAT] * wsm[t + 0];
        a1 += fp[(size_t)(t + 1) * FEAT] * wsm[t + 1];
        a2 += fp[(size_t)(t + 2) * FEAT] * wsm[t + 2];
        a3 += fp[(size_t)(t + 3) * FEAT] * wsm[t + 3];
    }
    out[(size_t)b * FEAT + f] = (a0 + a1) + (a2 + a3);
}

// ---------------------------------------------------------------------------
// Launch. d_out layout: [0, B*FEAT) attn_feats, [B*FEAT, B*FEAT + B*T) weights.
// Staging trick (no d_ws dependency):
//   - Whb (B*K = 32768 floats) lives in the weights region until k3 overwrites it.
//   - energy partials (4*B*T = 131072 floats) live in the attn region until k4
//     overwrites it. All kernels are sequential on `stream`, so this is safe.
// ---------------------------------------------------------------------------
extern "C" void kernel_launch(void* const* d_in, const int* in_sizes, int n_in,
                              void* d_out, int out_size, void* d_ws, size_t ws_size,
                              hipStream_t stream) {
    const float* hidden = (const float*)d_in[0];
    const float* feats  = (const float*)d_in[1];
    const float* W      = (const float*)d_in[2];
    const float* U      = (const float*)d_in[3];
    const float* bias   = (const float*)d_in[4];
    const float* wvec   = (const float*)d_in[5];

    float* out        = (float*)d_out;
    float* attn_out   = out;                        // B*FEAT floats
    float* weights_out = out + (size_t)BATCH * FEAT; // B*T floats
    float* whb        = weights_out;                 // staged (dead after k2)
    float* partial    = attn_out;                    // staged (dead after k3)

    k1_whb<<<dim3(KDIM / 4, BATCH), 256, 0, stream>>>(hidden, W, bias, whb);
    k2_energy<<<dim3((BATCH * TDIM) / BM, KDIM / BN), 256, 0, stream>>>(
        feats, U, whb, wvec, partial);
    k3_softmax<<<dim3(BATCH), 512, 0, stream>>>(partial, weights_out);
    k4_pool<<<dim3(FEAT / 256, BATCH), 256, 0, stream>>>(feats, weights_out, attn_out);
}

// Round 2
// 560.595 us; speedup vs baseline: 2.0572x; 2.0572x over previous
//
#include <hip/hip_runtime.h>
#include <hip/hip_bf16.h>
#include <math.h>

// Problem constants (from reference)
#define BATCH 64
#define TDIM 512
#define FEAT 2048
#define HID 1024
#define KDIM 512
#define MROWS (BATCH * TDIM)  // 32768 flat feats rows

typedef __attribute__((ext_vector_type(8))) short short8;
typedef __attribute__((ext_vector_type(4))) float floatx4;

// global -> LDS direct DMA, 16B per lane; LDS dest is wave-uniform base + lane*16
#define GLL16(g, l)                                                     \
    __builtin_amdgcn_global_load_lds(                                   \
        (const __attribute__((address_space(1))) void*)(g),             \
        (__attribute__((address_space(3))) void*)(l), 16, 0, 0)

// ---------------------------------------------------------------------------
// f32 -> bf16 (round-to-nearest-even)
// ---------------------------------------------------------------------------
__device__ __forceinline__ unsigned short f2bf(float x) {
    unsigned int u = __float_as_uint(x);
    u += 0x7FFFu + ((u >> 16) & 1u);
    return (unsigned short)(u >> 16);
}

__global__ __launch_bounds__(256) void k_convert(const float* __restrict__ src,
                                                 unsigned short* __restrict__ dst,
                                                 int n4) {
    int stride = gridDim.x * blockDim.x;
    for (int i = blockIdx.x * blockDim.x + threadIdx.x; i < n4; i += stride) {
        float4 v = ((const float4*)src)[i];
        ushort4 o;
        o.x = f2bf(v.x); o.y = f2bf(v.y); o.z = f2bf(v.z); o.w = f2bf(v.w);
        ((ushort4*)dst)[i] = o;
    }
}

// ---------------------------------------------------------------------------
// k1: Whb[b,k] = sum_h hidden[b,h] * W[k,h] + bias[k]
// ---------------------------------------------------------------------------
__global__ __launch_bounds__(256) void k1_whb(const float* __restrict__ hidden,
                                              const float* __restrict__ W,
                                              const float* __restrict__ bias,
                                              float* __restrict__ whb) {
    int b = blockIdx.y;
    int k = blockIdx.x * 4 + (threadIdx.x >> 6);
    int lane = threadIdx.x & 63;
    const float* hrow = hidden + (size_t)b * HID;
    const float* wrow = W + (size_t)k * HID;
    float acc = 0.f;
    #pragma unroll 4
    for (int h = lane; h < HID; h += 64) acc += hrow[h] * wrow[h];
    #pragma unroll
    for (int off = 32; off > 0; off >>= 1) acc += __shfl_down(acc, off, 64);
    if (lane == 0) whb[b * KDIM + k] = acc + bias[k];
}

// ---------------------------------------------------------------------------
// k2_mfma: bf16 MFMA GEMM (m97 structure) + fused tanh/dot(w) epilogue
//   S[m][n] = sum_f featsBf[m][f] * uBf[n][f]
//   partial[by][m] = sum_{n in this block's 128} tanh(S + Whb[b][n]) * w[n]
// 128x128 tile, BK=32, 256 threads = 4 waves (2x2), 4x4 MFMA tiles per wave.
// grid (MROWS/128 = 256, KDIM/128 = 4); 64 K-iterations.
// ---------------------------------------------------------------------------
__global__ __launch_bounds__(256) void k2_mfma(const unsigned short* __restrict__ fB,
                                               const unsigned short* __restrict__ uB,
                                               const float* __restrict__ whb,
                                               const float* __restrict__ wvec,
                                               float* __restrict__ partial) {
    // Unpadded: global_load_lds writes lane i at base + i*16 — layout must be
    // exactly [row][k] row-major, 64B rows (padding breaks the DMA mapping).
    __shared__ unsigned short As[128 * 32];
    __shared__ unsigned short Bs[128 * 32];
    __shared__ float sums[2][128];

    const int tid  = threadIdx.x;
    const int wave = tid >> 6;
    const int lane = tid & 63;
    const int row0 = blockIdx.x * 128;
    const int k0   = blockIdx.y * 128;
    const int wm = wave >> 1, wn = wave & 1;
    const int col = lane & 15, quad = lane >> 4;

    // Staging: 512 chunks of 16B per matrix; wave w covers chunks [w*128, w*128+128)
    // in two wave-issues of 64. chunk c -> row c>>2, k-chunk c&3 (8 bf16 each).
    const int c0 = wave * 128 + lane;
    const int c1 = c0 + 64;
    const unsigned short* gA0 = fB + (size_t)(row0 + (c0 >> 2)) * FEAT + (c0 & 3) * 8;
    const unsigned short* gA1 = fB + (size_t)(row0 + (c1 >> 2)) * FEAT + (c1 & 3) * 8;
    const unsigned short* gB0 = uB + (size_t)(k0 + (c0 >> 2)) * FEAT + (c0 & 3) * 8;
    const unsigned short* gB1 = uB + (size_t)(k0 + (c1 >> 2)) * FEAT + (c1 & 3) * 8;
    unsigned short* lA0 = As + wave * 1024;       // elements; = wave*2048 bytes
    unsigned short* lA1 = lA0 + 512;              // +64 chunks * 16B
    unsigned short* lB0 = Bs + wave * 1024;
    unsigned short* lB1 = lB0 + 512;

    floatx4 acc[4][4];
    #pragma unroll
    for (int i = 0; i < 4; ++i)
        #pragma unroll
        for (int j = 0; j < 4; ++j) acc[i][j] = (floatx4){0.f, 0.f, 0.f, 0.f};

    for (int f0 = 0; f0 < FEAT; f0 += 32) {
        GLL16(gA0, lA0); GLL16(gA1, lA1);
        GLL16(gB0, lB0); GLL16(gB1, lB1);
        gA0 += 32; gA1 += 32; gB0 += 32; gB1 += 32;
        __syncthreads();  // compiler emits vmcnt(0) drain before s_barrier

        short8 af[4], bf[4];
        // A-operand layout: A[m = lane&15][k = quad*8 + j] -> 16B contiguous
        #pragma unroll
        for (int i = 0; i < 4; ++i)
            af[i] = *(const short8*)&As[(wm * 64 + i * 16 + col) * 32 + quad * 8];
        #pragma unroll
        for (int j = 0; j < 4; ++j)
            bf[j] = *(const short8*)&Bs[(wn * 64 + j * 16 + col) * 32 + quad * 8];
        #pragma unroll
        for (int i = 0; i < 4; ++i)
            #pragma unroll
            for (int j = 0; j < 4; ++j)
                acc[i][j] = __builtin_amdgcn_mfma_f32_16x16x32_bf16(
                    af[i], bf[j], acc[i][j], 0, 0, 0);
        __syncthreads();
    }

    // Epilogue. C/D layout: col = lane&15 (n), row = quad*4 + reg (m).
    const int b = row0 >> 9;  // T = 512
    float wk[4], hk[4];
    #pragma unroll
    for (int j = 0; j < 4; ++j) {
        int k = k0 + wn * 64 + j * 16 + col;
        wk[j] = wvec[k];
        hk[j] = whb[b * KDIM + k];
    }
    #pragma unroll
    for (int i = 0; i < 4; ++i) {
        #pragma unroll
        for (int r = 0; r < 4; ++r) {
            float s = 0.f;
            #pragma unroll
            for (int j = 0; j < 4; ++j)
                s += tanhf(acc[i][j][r] + hk[j]) * wk[j];
            // reduce over the 16 cols (lanes [quad*16, quad*16+16))
            #pragma unroll
            for (int off = 8; off > 0; off >>= 1)
                s += __shfl_down(s, off, 16);
            if (col == 0)
                sums[wn][wm * 64 + i * 16 + quad * 4 + r] = s;
        }
    }
    __syncthreads();
    if (tid < 128)
        partial[blockIdx.y * MROWS + row0 + tid] = sums[0][tid] + sums[1][tid];
}

// ---------------------------------------------------------------------------
// k2_energy: fp32 fallback (used only if ws_size can't hold bf16 copies)
// ---------------------------------------------------------------------------
#define BM 128
#define BN 128
#define BF 16
#define LDSPAD 4

__global__ __launch_bounds__(256) void k2_energy(const float* __restrict__ feats,
                                                 const float* __restrict__ U,
                                                 const float* __restrict__ whb,
                                                 const float* __restrict__ wvec,
                                                 float* __restrict__ partial) {
    __shared__ __align__(16) float As[BF][BM + LDSPAD];
    __shared__ __align__(16) float Us[BF][BN + LDSPAD];

    const int row0 = blockIdx.x * BM;
    const int k0   = blockIdx.y * BN;
    const int tid  = threadIdx.x;
    const int tx   = tid & 15;
    const int ty   = tid >> 4;

    float acc[8][8];
    #pragma unroll
    for (int i = 0; i < 8; ++i)
        #pragma unroll
        for (int j = 0; j < 8; ++j) acc[i][j] = 0.f;

    for (int f0 = 0; f0 < FEAT; f0 += BF) {
        #pragma unroll
        for (int l = 0; l < 2; ++l) {
            int li = tid + l * 256;
            int r  = li >> 2;
            int c4 = (li & 3) * 4;
            float4 av = *(const float4*)(feats + (size_t)(row0 + r) * FEAT + f0 + c4);
            float4 uv = *(const float4*)(U     + (size_t)(k0   + r) * FEAT + f0 + c4);
            As[c4 + 0][r] = av.x; As[c4 + 1][r] = av.y;
            As[c4 + 2][r] = av.z; As[c4 + 3][r] = av.w;
            Us[c4 + 0][r] = uv.x; Us[c4 + 1][r] = uv.y;
            Us[c4 + 2][r] = uv.z; Us[c4 + 3][r] = uv.w;
        }
        __syncthreads();
        #pragma unroll
        for (int kf = 0; kf < BF; ++kf) {
            float4 a0 = *(const float4*)&As[kf][ty * 8];
            float4 a1 = *(const float4*)&As[kf][ty * 8 + 4];
            float4 u0 = *(const float4*)&Us[kf][tx * 8];
            float4 u1 = *(const float4*)&Us[kf][tx * 8 + 4];
            float a[8] = {a0.x, a0.y, a0.z, a0.w, a1.x, a1.y, a1.z, a1.w};
            float u[8] = {u0.x, u0.y, u0.z, u0.w, u1.x, u1.y, u1.z, u1.w};
            #pragma unroll
            for (int i = 0; i < 8; ++i)
                #pragma unroll
                for (int j = 0; j < 8; ++j) acc[i][j] += a[i] * u[j];
        }
        __syncthreads();
    }

    const int b = row0 >> 9;
    float psum[8];
    #pragma unroll
    for (int i = 0; i < 8; ++i) {
        float s = 0.f;
        #pragma unroll
        for (int j = 0; j < 8; ++j) {
            int k = k0 + tx * 8 + j;
            s += tanhf(acc[i][j] + whb[b * KDIM + k]) * wvec[k];
        }
        psum[i] = s;
    }
    #pragma unroll
    for (int off = 8; off > 0; off >>= 1)
        #pragma unroll
        for (int i = 0; i < 8; ++i) psum[i] += __shfl_down(psum[i], off, 16);

    if (tx == 0) {
        int c = blockIdx.y;
        #pragma unroll
        for (int i = 0; i < 8; ++i)
            partial[c * MROWS + row0 + ty * 8 + i] = psum[i];
    }
}

// ---------------------------------------------------------------------------
// k3: energies = sum of 4 partials; softmax over T per batch -> weights
// ---------------------------------------------------------------------------
__global__ __launch_bounds__(512) void k3_softmax(const float* __restrict__ partial,
                                                  float* __restrict__ wout) {
    int b = blockIdx.x;
    int t = threadIdx.x;
    float e = 0.f;
    #pragma unroll
    for (int c = 0; c < 4; ++c) e += partial[c * MROWS + b * TDIM + t];

    __shared__ float sm[512];
    sm[t] = e;
    __syncthreads();
    #pragma unroll
    for (int s = 256; s > 0; s >>= 1) {
        if (t < s) sm[t] = fmaxf(sm[t], sm[t + s]);
        __syncthreads();
    }
    float m = sm[0];
    __syncthreads();
    float ex = __expf(e - m);
    sm[t] = ex;
    __syncthreads();
    #pragma unroll
    for (int s = 256; s > 0; s >>= 1) {
        if (t < s) sm[t] += sm[t + s];
        __syncthreads();
    }
    float inv = 1.f / sm[0];
    wout[b * TDIM + t] = ex * inv;
}

// ---------------------------------------------------------------------------
// k4: attn_feats[b,f] = sum_t feats[b,t,f] * weights[b,t]
// float4 per thread, 4 independent t-streams for MLP. grid (FEAT/1024, BATCH).
// ---------------------------------------------------------------------------
__global__ __launch_bounds__(256) void k4_pool(const float* __restrict__ feats,
                                               const float* __restrict__ weights,
                                               float* __restrict__ out) {
    int b = blockIdx.y;
    int f4 = (blockIdx.x * 256 + threadIdx.x) * 4;
    __shared__ float wsm[TDIM];
    wsm[threadIdx.x]       = weights[b * TDIM + threadIdx.x];
    wsm[threadIdx.x + 256] = weights[b * TDIM + 256 + threadIdx.x];
    __syncthreads();

    const float* fp = feats + (size_t)b * TDIM * FEAT + f4;
    float ax = 0.f, ay = 0.f, az = 0.f, aw = 0.f;
    float bx = 0.f, by = 0.f, bz = 0.f, bw = 0.f;
    for (int t = 0; t < TDIM; t += 4) {
        float4 v0 = *(const float4*)(fp + (size_t)(t + 0) * FEAT);
        float4 v1 = *(const float4*)(fp + (size_t)(t + 1) * FEAT);
        float4 v2 = *(const float4*)(fp + (size_t)(t + 2) * FEAT);
        float4 v3 = *(const float4*)(fp + (size_t)(t + 3) * FEAT);
        float w0 = wsm[t], w1 = wsm[t + 1], w2 = wsm[t + 2], w3 = wsm[t + 3];
        ax += v0.x * w0; ay += v0.y * w0; az += v0.z * w0; aw += v0.w * w0;
        bx += v1.x * w1; by += v1.y * w1; bz += v1.z * w1; bw += v1.w * w1;
        ax += v2.x * w2; ay += v2.y * w2; az += v2.z * w2; aw += v2.w * w2;
        bx += v3.x * w3; by += v3.y * w3; bz += v3.z * w3; bw += v3.w * w3;
    }
    float4 o;
    o.x = ax + bx; o.y = ay + by; o.z = az + bz; o.w = aw + bw;
    *(float4*)(out + (size_t)b * FEAT + f4) = o;
}

// ---------------------------------------------------------------------------
// Launch. d_out layout: [0, B*FEAT) attn_feats, [B*FEAT, +B*T) weights.
// Staging in d_out: Whb lives in the weights region (dead after k2); energy
// partials (4*B*T = B*FEAT floats exactly) live in the attn region (dead after
// k3). d_ws holds bf16 copies of feats/U when it's big enough (~130 MB);
// branch is on host-constant ws_size -> identical work every call (graph-safe).
// ---------------------------------------------------------------------------
extern "C" void kernel_launch(void* const* d_in, const int* in_sizes, int n_in,
                              void* d_out, int out_size, void* d_ws, size_t ws_size,
                              hipStream_t stream) {
    const float* hidden = (const float*)d_in[0];
    const float* feats  = (const float*)d_in[1];
    const float* W      = (const float*)d_in[2];
    const float* U      = (const float*)d_in[3];
    const float* bias   = (const float*)d_in[4];
    const float* wvec   = (const float*)d_in[5];

    float* out         = (float*)d_out;
    float* attn_out    = out;                          // B*FEAT floats
    float* weights_out = out + (size_t)BATCH * FEAT;   // B*T floats
    float* whb         = weights_out;                  // staged (dead after k2)
    float* partial     = attn_out;                     // staged (dead after k3)

    const size_t featsN = (size_t)MROWS * FEAT;        // 67,108,864
    const size_t uN     = (size_t)KDIM * FEAT;         // 1,048,576
    const bool bf16path = ws_size >= (featsN + uN) * sizeof(unsigned short);

    k1_whb<<<dim3(KDIM / 4, BATCH), 256, 0, stream>>>(hidden, W, bias, whb);

    if (bf16path) {
        unsigned short* fBf = (unsigned short*)d_ws;
        unsigned short* uBf = fBf + featsN;
        k_convert<<<1024, 256, 0, stream>>>(feats, fBf, (int)(featsN / 4));
        k_convert<<<256, 256, 0, stream>>>(U, uBf, (int)(uN / 4));
        k2_mfma<<<dim3(MROWS / 128, KDIM / 128), 256, 0, stream>>>(
            fBf, uBf, whb, wvec, partial);
    } else {
        k2_energy<<<dim3(MROWS / 128, KDIM / 128), 256, 0, stream>>>(
            feats, U, whb, wvec, partial);
    }

    k3_softmax<<<dim3(BATCH), 512, 0, stream>>>(partial, weights_out);
    k4_pool<<<dim3(FEAT / 1024, BATCH), 256, 0, stream>>>(feats, weights_out, attn_out);
}

// Round 3
// 555.167 us; speedup vs baseline: 2.0773x; 1.0098x over previous
//
#include <hip/hip_runtime.h>
#include <hip/hip_bf16.h>
#include <math.h>

// Problem constants (from reference)
#define BATCH 64
#define TDIM 512
#define FEAT 2048
#define HID 1024
#define KDIM 512
#define MROWS (BATCH * TDIM)  // 32768 flat feats rows
#define TCH 8                 // k4 time-chunks
#define TCLEN (TDIM / TCH)    // 64 t per chunk

typedef __attribute__((ext_vector_type(8))) short short8;
typedef __attribute__((ext_vector_type(4))) float floatx4;

// global -> LDS direct DMA, 16B per lane; LDS dest is wave-uniform base + lane*16
#define GLL16(g, l)                                                     \
    __builtin_amdgcn_global_load_lds(                                   \
        (const __attribute__((address_space(1))) void*)(g),             \
        (__attribute__((address_space(3))) void*)(l), 16, 0, 0)

// ---------------------------------------------------------------------------
// f32 -> bf16 (round-to-nearest-even)
// ---------------------------------------------------------------------------
__device__ __forceinline__ unsigned short f2bf(float x) {
    unsigned int u = __float_as_uint(x);
    u += 0x7FFFu + ((u >> 16) & 1u);
    return (unsigned short)(u >> 16);
}

__global__ __launch_bounds__(256) void k_convert(const float* __restrict__ src,
                                                 unsigned short* __restrict__ dst,
                                                 int n4) {
    int stride = gridDim.x * blockDim.x;
    for (int i = blockIdx.x * blockDim.x + threadIdx.x; i < n4; i += stride) {
        float4 v = ((const float4*)src)[i];
        ushort4 o;
        o.x = f2bf(v.x); o.y = f2bf(v.y); o.z = f2bf(v.z); o.w = f2bf(v.w);
        ((ushort4*)dst)[i] = o;
    }
}

// ---------------------------------------------------------------------------
// k1: Whb[b,k] = sum_h hidden[b,h] * W[k,h] + bias[k]
// ---------------------------------------------------------------------------
__global__ __launch_bounds__(256) void k1_whb(const float* __restrict__ hidden,
                                              const float* __restrict__ W,
                                              const float* __restrict__ bias,
                                              float* __restrict__ whb) {
    int b = blockIdx.y;
    int k = blockIdx.x * 4 + (threadIdx.x >> 6);
    int lane = threadIdx.x & 63;
    const float* hrow = hidden + (size_t)b * HID;
    const float* wrow = W + (size_t)k * HID;
    float acc = 0.f;
    #pragma unroll 4
    for (int h = lane; h < HID; h += 64) acc += hrow[h] * wrow[h];
    #pragma unroll
    for (int off = 32; off > 0; off >>= 1) acc += __shfl_down(acc, off, 64);
    if (lane == 0) whb[b * KDIM + k] = acc + bias[k];
}

// ---------------------------------------------------------------------------
// k2_mfma: bf16 MFMA GEMM + fused tanh/dot(w) epilogue, XOR-swizzled LDS.
//   Tile 128x128, BK=32, 256 thr = 4 waves (2x2), 4x4 16x16x32 MFMAs/wave.
// LDS chunk swizzle: global chunk (row, q) stored at slot (row, q^((row>>1)&3)).
// Read side: lane (quad,col) wants (m, quad) -> slot (m, quad^((col>>1)&3))
// (wm*64 and i*16 contribute 0 mod 4 to m>>1). Spreads b128 start-banks over
// all eight 4-bank spans per 32-lane phase -> conflict-free-equivalent.
// ---------------------------------------------------------------------------
__global__ __launch_bounds__(256) void k2_mfma(const unsigned short* __restrict__ fB,
                                               const unsigned short* __restrict__ uB,
                                               const float* __restrict__ whb,
                                               const float* __restrict__ wvec,
                                               float* __restrict__ partial) {
    __shared__ unsigned short As[128 * 32];  // unpadded: DMA lane-mapping
    __shared__ unsigned short Bs[128 * 32];
    __shared__ float sums[2][128];

    const int tid  = threadIdx.x;
    const int wave = tid >> 6;
    const int lane = tid & 63;
    const int row0 = blockIdx.x * 128;
    const int k0   = blockIdx.y * 128;
    const int wm = wave >> 1, wn = wave & 1;
    const int col = lane & 15, quad = lane >> 4;

    // Staging: 512 16B-chunks per matrix; slot c holds global chunk
    // (row = c>>2, q = (c&3) ^ ((row>>1)&3)).
    const int c0 = wave * 128 + lane;
    const int c1 = c0 + 64;
    const int r0c = c0 >> 2, r1c = c1 >> 2;
    const int q0 = (c0 & 3) ^ ((r0c >> 1) & 3);
    const int q1 = (c1 & 3) ^ ((r1c >> 1) & 3);
    const unsigned short* gA0 = fB + (size_t)(row0 + r0c) * FEAT + q0 * 8;
    const unsigned short* gA1 = fB + (size_t)(row0 + r1c) * FEAT + q1 * 8;
    const unsigned short* gB0 = uB + (size_t)(k0 + r0c) * FEAT + q0 * 8;
    const unsigned short* gB1 = uB + (size_t)(k0 + r1c) * FEAT + q1 * 8;
    unsigned short* lA0 = As + wave * 1024;
    unsigned short* lA1 = lA0 + 512;
    unsigned short* lB0 = Bs + wave * 1024;
    unsigned short* lB1 = lB0 + 512;

    const int sw = (quad ^ ((col >> 1) & 3)) * 8;  // swizzled k-offset (elems)

    floatx4 acc[4][4];
    #pragma unroll
    for (int i = 0; i < 4; ++i)
        #pragma unroll
        for (int j = 0; j < 4; ++j) acc[i][j] = (floatx4){0.f, 0.f, 0.f, 0.f};

    for (int f0 = 0; f0 < FEAT; f0 += 32) {
        GLL16(gA0, lA0); GLL16(gA1, lA1);
        GLL16(gB0, lB0); GLL16(gB1, lB1);
        gA0 += 32; gA1 += 32; gB0 += 32; gB1 += 32;
        __syncthreads();

        short8 af[4], bf[4];
        #pragma unroll
        for (int i = 0; i < 4; ++i)
            af[i] = *(const short8*)&As[(wm * 64 + i * 16 + col) * 32 + sw];
        #pragma unroll
        for (int j = 0; j < 4; ++j)
            bf[j] = *(const short8*)&Bs[(wn * 64 + j * 16 + col) * 32 + sw];
        #pragma unroll
        for (int i = 0; i < 4; ++i)
            #pragma unroll
            for (int j = 0; j < 4; ++j)
                acc[i][j] = __builtin_amdgcn_mfma_f32_16x16x32_bf16(
                    af[i], bf[j], acc[i][j], 0, 0, 0);
        __syncthreads();
    }

    // Epilogue. C/D layout: col = lane&15 (n), row = quad*4 + reg (m).
    const int b = row0 >> 9;  // T = 512
    float wk[4], hk[4];
    #pragma unroll
    for (int j = 0; j < 4; ++j) {
        int k = k0 + wn * 64 + j * 16 + col;
        wk[j] = wvec[k];
        hk[j] = whb[b * KDIM + k];
    }
    #pragma unroll
    for (int i = 0; i < 4; ++i) {
        #pragma unroll
        for (int r = 0; r < 4; ++r) {
            float s = 0.f;
            #pragma unroll
            for (int j = 0; j < 4; ++j)
                s += tanhf(acc[i][j][r] + hk[j]) * wk[j];
            #pragma unroll
            for (int off = 8; off > 0; off >>= 1)
                s += __shfl_down(s, off, 16);
            if (col == 0)
                sums[wn][wm * 64 + i * 16 + quad * 4 + r] = s;
        }
    }
    __syncthreads();
    if (tid < 128)
        partial[blockIdx.y * MROWS + row0 + tid] = sums[0][tid] + sums[1][tid];
}

// ---------------------------------------------------------------------------
// k2_energy: fp32 fallback (used only if ws_size can't hold bf16 copies)
// ---------------------------------------------------------------------------
#define BM 128
#define BN 128
#define BF 16
#define LDSPAD 4

__global__ __launch_bounds__(256) void k2_energy(const float* __restrict__ feats,
                                                 const float* __restrict__ U,
                                                 const float* __restrict__ whb,
                                                 const float* __restrict__ wvec,
                                                 float* __restrict__ partial) {
    __shared__ __align__(16) float As[BF][BM + LDSPAD];
    __shared__ __align__(16) float Us[BF][BN + LDSPAD];

    const int row0 = blockIdx.x * BM;
    const int k0   = blockIdx.y * BN;
    const int tid  = threadIdx.x;
    const int tx   = tid & 15;
    const int ty   = tid >> 4;

    float acc[8][8];
    #pragma unroll
    for (int i = 0; i < 8; ++i)
        #pragma unroll
        for (int j = 0; j < 8; ++j) acc[i][j] = 0.f;

    for (int f0 = 0; f0 < FEAT; f0 += BF) {
        #pragma unroll
        for (int l = 0; l < 2; ++l) {
            int li = tid + l * 256;
            int r  = li >> 2;
            int c4 = (li & 3) * 4;
            float4 av = *(const float4*)(feats + (size_t)(row0 + r) * FEAT + f0 + c4);
            float4 uv = *(const float4*)(U     + (size_t)(k0   + r) * FEAT + f0 + c4);
            As[c4 + 0][r] = av.x; As[c4 + 1][r] = av.y;
            As[c4 + 2][r] = av.z; As[c4 + 3][r] = av.w;
            Us[c4 + 0][r] = uv.x; Us[c4 + 1][r] = uv.y;
            Us[c4 + 2][r] = uv.z; Us[c4 + 3][r] = uv.w;
        }
        __syncthreads();
        #pragma unroll
        for (int kf = 0; kf < BF; ++kf) {
            float4 a0 = *(const float4*)&As[kf][ty * 8];
            float4 a1 = *(const float4*)&As[kf][ty * 8 + 4];
            float4 u0 = *(const float4*)&Us[kf][tx * 8];
            float4 u1 = *(const float4*)&Us[kf][tx * 8 + 4];
            float a[8] = {a0.x, a0.y, a0.z, a0.w, a1.x, a1.y, a1.z, a1.w};
            float u[8] = {u0.x, u0.y, u0.z, u0.w, u1.x, u1.y, u1.z, u1.w};
            #pragma unroll
            for (int i = 0; i < 8; ++i)
                #pragma unroll
                for (int j = 0; j < 8; ++j) acc[i][j] += a[i] * u[j];
        }
        __syncthreads();
    }

    const int b = row0 >> 9;
    float psum[8];
    #pragma unroll
    for (int i = 0; i < 8; ++i) {
        float s = 0.f;
        #pragma unroll
        for (int j = 0; j < 8; ++j) {
            int k = k0 + tx * 8 + j;
            s += tanhf(acc[i][j] + whb[b * KDIM + k]) * wvec[k];
        }
        psum[i] = s;
    }
    #pragma unroll
    for (int off = 8; off > 0; off >>= 1)
        #pragma unroll
        for (int i = 0; i < 8; ++i) psum[i] += __shfl_down(psum[i], off, 16);

    if (tx == 0) {
        int c = blockIdx.y;
        #pragma unroll
        for (int i = 0; i < 8; ++i)
            partial[c * MROWS + row0 + ty * 8 + i] = psum[i];
    }
}

// ---------------------------------------------------------------------------
// k3: energies = sum of 4 partials; softmax over T per batch -> weights
// ---------------------------------------------------------------------------
__global__ __launch_bounds__(512) void k3_softmax(const float* __restrict__ partial,
                                                  float* __restrict__ wout) {
    int b = blockIdx.x;
    int t = threadIdx.x;
    float e = 0.f;
    #pragma unroll
    for (int c = 0; c < 4; ++c) e += partial[c * MROWS + b * TDIM + t];

    __shared__ float sm[512];
    sm[t] = e;
    __syncthreads();
    #pragma unroll
    for (int s = 256; s > 0; s >>= 1) {
        if (t < s) sm[t] = fmaxf(sm[t], sm[t + s]);
        __syncthreads();
    }
    float m = sm[0];
    __syncthreads();
    float ex = __expf(e - m);
    sm[t] = ex;
    __syncthreads();
    #pragma unroll
    for (int s = 256; s > 0; s >>= 1) {
        if (t < s) sm[t] += sm[t + s];
        __syncthreads();
    }
    float inv = 1.f / sm[0];
    wout[b * TDIM + t] = ex * inv;
}

// ---------------------------------------------------------------------------
// k4_partial: T-chunked weighted pooling. grid (FEAT/1024, TCH, BATCH) = 1024
// blocks (16 waves/CU -> enough MLP to approach HBM BW). Each block: 1024
// consecutive f, TCLEN=64 time steps. partial4[(tc*BATCH + b)*FEAT + f].
// ---------------------------------------------------------------------------
__global__ __launch_bounds__(256) void k4_partial(const float* __restrict__ feats,
                                                  const float* __restrict__ weights,
                                                  float* __restrict__ partial4) {
    int b  = blockIdx.z;
    int t0 = blockIdx.y * TCLEN;
    int f4 = (blockIdx.x * 256 + threadIdx.x) * 4;
    __shared__ float wsm[TCLEN];
    if (threadIdx.x < TCLEN) wsm[threadIdx.x] = weights[b * TDIM + t0 + threadIdx.x];
    __syncthreads();

    const float* fp = feats + (size_t)b * TDIM * FEAT + (size_t)t0 * FEAT + f4;
    float ax = 0.f, ay = 0.f, az = 0.f, aw = 0.f;
    float bx = 0.f, by = 0.f, bz = 0.f, bw = 0.f;
    #pragma unroll 4
    for (int t = 0; t < TCLEN; t += 4) {
        float4 v0 = *(const float4*)(fp + (size_t)(t + 0) * FEAT);
        float4 v1 = *(const float4*)(fp + (size_t)(t + 1) * FEAT);
        float4 v2 = *(const float4*)(fp + (size_t)(t + 2) * FEAT);
        float4 v3 = *(const float4*)(fp + (size_t)(t + 3) * FEAT);
        float w0 = wsm[t], w1 = wsm[t + 1], w2 = wsm[t + 2], w3 = wsm[t + 3];
        ax += v0.x * w0; ay += v0.y * w0; az += v0.z * w0; aw += v0.w * w0;
        bx += v1.x * w1; by += v1.y * w1; bz += v1.z * w1; bw += v1.w * w1;
        ax += v2.x * w2; ay += v2.y * w2; az += v2.z * w2; aw += v2.w * w2;
        bx += v3.x * w3; by += v3.y * w3; bz += v3.z * w3; bw += v3.w * w3;
    }
    float4 o;
    o.x = ax + bx; o.y = ay + by; o.z = az + bz; o.w = aw + bw;
    *(float4*)(partial4 + ((size_t)blockIdx.y * BATCH + b) * FEAT + f4) = o;
}

__global__ __launch_bounds__(256) void k5_reduce(const float* __restrict__ partial4,
                                                 float* __restrict__ out) {
    int i4 = blockIdx.x * 256 + threadIdx.x;  // float4 index into B*FEAT
    float4 s = ((const float4*)partial4)[i4];
    #pragma unroll
    for (int c = 1; c < TCH; ++c) {
        float4 v = ((const float4*)partial4)[(size_t)c * (BATCH * FEAT / 4) + i4];
        s.x += v.x; s.y += v.y; s.z += v.z; s.w += v.w;
    }
    ((float4*)out)[i4] = s;
}

// ---------------------------------------------------------------------------
// k4_direct: single-stage fallback (no ws needed)
// ---------------------------------------------------------------------------
__global__ __launch_bounds__(256) void k4_direct(const float* __restrict__ feats,
                                                 const float* __restrict__ weights,
                                                 float* __restrict__ out) {
    int b = blockIdx.y;
    int f4 = (blockIdx.x * 256 + threadIdx.x) * 4;
    __shared__ float wsm[TDIM];
    wsm[threadIdx.x]       = weights[b * TDIM + threadIdx.x];
    wsm[threadIdx.x + 256] = weights[b * TDIM + 256 + threadIdx.x];
    __syncthreads();

    const float* fp = feats + (size_t)b * TDIM * FEAT + f4;
    float ax = 0.f, ay = 0.f, az = 0.f, aw = 0.f;
    for (int t = 0; t < TDIM; ++t) {
        float4 v = *(const float4*)(fp + (size_t)t * FEAT);
        float w = wsm[t];
        ax += v.x * w; ay += v.y * w; az += v.z * w; aw += v.w * w;
    }
    float4 o = {ax, ay, az, aw};
    *(float4*)(out + (size_t)b * FEAT + f4) = o;
}

// ---------------------------------------------------------------------------
// Launch. d_out: [0, B*FEAT) attn_feats, [B*FEAT, +B*T) weights.
// d_out staging: Whb in weights region (dead after k2); energy partials in
// attn region (dead after k3). d_ws: bf16 feats (128 MB) + bf16 U (1 MB) +
// pooling partials (4 MB). Branch on host-constant ws_size (graph-safe).
// ---------------------------------------------------------------------------
extern "C" void kernel_launch(void* const* d_in, const int* in_sizes, int n_in,
                              void* d_out, int out_size, void* d_ws, size_t ws_size,
                              hipStream_t stream) {
    const float* hidden = (const float*)d_in[0];
    const float* feats  = (const float*)d_in[1];
    const float* W      = (const float*)d_in[2];
    const float* U      = (const float*)d_in[3];
    const float* bias   = (const float*)d_in[4];
    const float* wvec   = (const float*)d_in[5];

    float* out         = (float*)d_out;
    float* attn_out    = out;
    float* weights_out = out + (size_t)BATCH * FEAT;
    float* whb         = weights_out;  // staged (dead after k2)
    float* partial     = attn_out;     // staged (dead after k3)

    const size_t featsN = (size_t)MROWS * FEAT;
    const size_t uN     = (size_t)KDIM * FEAT;
    const size_t bf16Bytes = (featsN + uN) * sizeof(unsigned short);
    const size_t poolBytes = (size_t)TCH * BATCH * FEAT * sizeof(float);
    const bool fast = ws_size >= bf16Bytes + poolBytes;

    k1_whb<<<dim3(KDIM / 4, BATCH), 256, 0, stream>>>(hidden, W, bias, whb);

    if (fast) {
        unsigned short* fBf = (unsigned short*)d_ws;
        unsigned short* uBf = fBf + featsN;
        float* pool4 = (float*)((char*)d_ws + bf16Bytes);
        k_convert<<<1024, 256, 0, stream>>>(feats, fBf, (int)(featsN / 4));
        k_convert<<<256, 256, 0, stream>>>(U, uBf, (int)(uN / 4));
        k2_mfma<<<dim3(MROWS / 128, KDIM / 128), 256, 0, stream>>>(
            fBf, uBf, whb, wvec, partial);
        k3_softmax<<<dim3(BATCH), 512, 0, stream>>>(partial, weights_out);
        k4_partial<<<dim3(FEAT / 1024, TCH, BATCH), 256, 0, stream>>>(
            feats, weights_out, pool4);
        k5_reduce<<<dim3(BATCH * FEAT / 4 / 256), 256, 0, stream>>>(pool4, attn_out);
    } else {
        k2_energy<<<dim3(MROWS / 128, KDIM / 128), 256, 0, stream>>>(
            feats, U, whb, wvec, partial);
        k3_softmax<<<dim3(BATCH), 512, 0, stream>>>(partial, weights_out);
        k4_direct<<<dim3(FEAT / 1024, BATCH), 256, 0, stream>>>(
            feats, weights_out, attn_out);
    }
}

// Round 4
// 547.060 us; speedup vs baseline: 2.1081x; 1.0148x over previous
//
#include <hip/hip_runtime.h>
#include <hip/hip_bf16.h>
#include <math.h>

// Problem constants (from reference)
#define BATCH 64
#define TDIM 512
#define FEAT 2048
#define HID 1024
#define KDIM 512
#define MROWS (BATCH * TDIM)  // 32768 flat feats rows
#define TCH 16                // k4 time-chunks
#define TCLEN (TDIM / TCH)    // 32 t per chunk

typedef __attribute__((ext_vector_type(8))) short short8;
typedef __attribute__((ext_vector_type(4))) float floatx4;

// global -> LDS direct DMA, 16B per lane; LDS dest is wave-uniform base,
// lane i lands at base + i*16 (per-lane LDS address is NOT honored).
#define GLL16(g, l)                                                     \
    __builtin_amdgcn_global_load_lds(                                   \
        (const __attribute__((address_space(1))) void*)(g),             \
        (__attribute__((address_space(3))) void*)(l), 16, 0, 0)

// ---------------------------------------------------------------------------
// f32 -> bf16 (round-to-nearest-even)
// ---------------------------------------------------------------------------
__device__ __forceinline__ unsigned short f2bf(float x) {
    unsigned int u = __float_as_uint(x);
    u += 0x7FFFu + ((u >> 16) & 1u);
    return (unsigned short)(u >> 16);
}

// One kernel converts feats then U (grid-stride over the concatenation).
__global__ __launch_bounds__(256) void k_convert2(const float* __restrict__ feats,
                                                  const float* __restrict__ U,
                                                  unsigned short* __restrict__ fB,
                                                  unsigned short* __restrict__ uB,
                                                  int n4f, int n4tot) {
    int stride = gridDim.x * blockDim.x;
    for (int i = blockIdx.x * blockDim.x + threadIdx.x; i < n4tot; i += stride) {
        const float4* src = (i < n4f) ? (const float4*)feats + i
                                      : (const float4*)U + (i - n4f);
        ushort4* dst = (i < n4f) ? (ushort4*)fB + i
                                 : (ushort4*)uB + (i - n4f);
        float4 v = *src;
        ushort4 o;
        o.x = f2bf(v.x); o.y = f2bf(v.y); o.z = f2bf(v.z); o.w = f2bf(v.w);
        *dst = o;
    }
}

// ---------------------------------------------------------------------------
// k1: Whb[b,k] = sum_h hidden[b,h] * W[k,h] + bias[k]
// ---------------------------------------------------------------------------
__global__ __launch_bounds__(256) void k1_whb(const float* __restrict__ hidden,
                                              const float* __restrict__ W,
                                              const float* __restrict__ bias,
                                              float* __restrict__ whb) {
    int b = blockIdx.y;
    int k = blockIdx.x * 4 + (threadIdx.x >> 6);
    int lane = threadIdx.x & 63;
    const float* hrow = hidden + (size_t)b * HID;
    const float* wrow = W + (size_t)k * HID;
    float acc = 0.f;
    #pragma unroll 4
    for (int h = lane; h < HID; h += 64) acc += hrow[h] * wrow[h];
    #pragma unroll
    for (int off = 32; off > 0; off >>= 1) acc += __shfl_down(acc, off, 64);
    if (lane == 0) whb[b * KDIM + k] = acc + bias[k];
}

// ---------------------------------------------------------------------------
// k2_mfma: bf16 MFMA GEMM + fused tanh/dot(w) epilogue.
// Tile M=256 x N=128, BK=32, 256 thr = 4 waves (2x2), wave-tile 128x64
// (8x4 16x16x32 MFMAs). 2 blocks/CU (launch_bounds 256,2). Grid (128, 4).
// XOR chunk swizzle: LDS slot s holds global chunk (row=s>>2, q=(s&3)^((row>>1)&3));
// read offset sw = (quad^((col>>1)&3))*8 (wm/i terms are 0 mod 8 in m).
// ---------------------------------------------------------------------------
__global__ __launch_bounds__(256, 2) void k2_mfma(const unsigned short* __restrict__ fB,
                                                  const unsigned short* __restrict__ uB,
                                                  const float* __restrict__ whb,
                                                  const float* __restrict__ wvec,
                                                  float* __restrict__ partial) {
    __shared__ unsigned short As[256 * 32];  // 16 KB, unpadded (DMA layout)
    __shared__ unsigned short Bs[128 * 32];  // 8 KB
    __shared__ float sums[2][256];

    const int tid  = threadIdx.x;
    const int wave = tid >> 6;
    const int lane = tid & 63;
    const int row0 = blockIdx.x * 256;
    const int k0   = blockIdx.y * 128;
    const int wm = wave >> 1, wn = wave & 1;
    const int col = lane & 15, quad = lane >> 4;

    // A: 1024 slots of 16B; this thread fills slots wave*256 + lane + {0,64,128,192}.
    // B: 512 slots; slots wave*128 + lane + {0,64}.
    const unsigned short* gA[4];
    unsigned short* lA[4];
    #pragma unroll
    for (int g = 0; g < 4; ++g) {
        int s = wave * 256 + g * 64 + lane;
        int r = s >> 2;
        int q = (s & 3) ^ ((r >> 1) & 3);
        gA[g] = fB + (size_t)(row0 + r) * FEAT + q * 8;
        lA[g] = As + (wave * 256 + g * 64) * 8;  // wave-uniform base
    }
    const unsigned short* gBp[2];
    unsigned short* lB[2];
    #pragma unroll
    for (int g = 0; g < 2; ++g) {
        int s = wave * 128 + g * 64 + lane;
        int r = s >> 2;
        int q = (s & 3) ^ ((r >> 1) & 3);
        gBp[g] = uB + (size_t)(k0 + r) * FEAT + q * 8;
        lB[g] = Bs + (wave * 128 + g * 64) * 8;
    }

    const int sw = (quad ^ ((col >> 1) & 3)) * 8;

    floatx4 acc[8][4];
    #pragma unroll
    for (int i = 0; i < 8; ++i)
        #pragma unroll
        for (int j = 0; j < 4; ++j) acc[i][j] = (floatx4){0.f, 0.f, 0.f, 0.f};

    for (int f0 = 0; f0 < FEAT; f0 += 32) {
        #pragma unroll
        for (int g = 0; g < 4; ++g) { GLL16(gA[g], lA[g]); gA[g] += 32; }
        #pragma unroll
        for (int g = 0; g < 2; ++g) { GLL16(gBp[g], lB[g]); gBp[g] += 32; }
        __syncthreads();

        short8 af[8], bf[4];
        #pragma unroll
        for (int i = 0; i < 8; ++i)
            af[i] = *(const short8*)&As[(wm * 128 + i * 16 + col) * 32 + sw];
        #pragma unroll
        for (int j = 0; j < 4; ++j)
            bf[j] = *(const short8*)&Bs[(wn * 64 + j * 16 + col) * 32 + sw];
        #pragma unroll
        for (int i = 0; i < 8; ++i)
            #pragma unroll
            for (int j = 0; j < 4; ++j)
                acc[i][j] = __builtin_amdgcn_mfma_f32_16x16x32_bf16(
                    af[i], bf[j], acc[i][j], 0, 0, 0);
        __syncthreads();
    }

    // Epilogue. C/D layout: col = lane&15 (n), row = quad*4 + reg (m).
    const int b = row0 >> 9;  // 256-row block stays within one batch (T=512)
    float wk[4], hk[4];
    #pragma unroll
    for (int j = 0; j < 4; ++j) {
        int k = k0 + wn * 64 + j * 16 + col;
        wk[j] = wvec[k];
        hk[j] = whb[b * KDIM + k];
    }
    #pragma unroll
    for (int i = 0; i < 8; ++i) {
        #pragma unroll
        for (int r = 0; r < 4; ++r) {
            float s = 0.f;
            #pragma unroll
            for (int j = 0; j < 4; ++j)
                s += tanhf(acc[i][j][r] + hk[j]) * wk[j];
            #pragma unroll
            for (int off = 8; off > 0; off >>= 1)
                s += __shfl_down(s, off, 16);
            if (col == 0)
                sums[wn][wm * 128 + i * 16 + quad * 4 + r] = s;
        }
    }
    __syncthreads();
    partial[blockIdx.y * MROWS + row0 + tid] = sums[0][tid] + sums[1][tid];
}

// ---------------------------------------------------------------------------
// k2_energy: fp32 fallback (used only if ws_size can't hold bf16 copies)
// ---------------------------------------------------------------------------
#define BM 128
#define BN 128
#define BF 16
#define LDSPAD 4

__global__ __launch_bounds__(256) void k2_energy(const float* __restrict__ feats,
                                                 const float* __restrict__ U,
                                                 const float* __restrict__ whb,
                                                 const float* __restrict__ wvec,
                                                 float* __restrict__ partial) {
    __shared__ __align__(16) float As[BF][BM + LDSPAD];
    __shared__ __align__(16) float Us[BF][BN + LDSPAD];

    const int row0 = blockIdx.x * BM;
    const int k0   = blockIdx.y * BN;
    const int tid  = threadIdx.x;
    const int tx   = tid & 15;
    const int ty   = tid >> 4;

    float acc[8][8];
    #pragma unroll
    for (int i = 0; i < 8; ++i)
        #pragma unroll
        for (int j = 0; j < 8; ++j) acc[i][j] = 0.f;

    for (int f0 = 0; f0 < FEAT; f0 += BF) {
        #pragma unroll
        for (int l = 0; l < 2; ++l) {
            int li = tid + l * 256;
            int r  = li >> 2;
            int c4 = (li & 3) * 4;
            float4 av = *(const float4*)(feats + (size_t)(row0 + r) * FEAT + f0 + c4);
            float4 uv = *(const float4*)(U     + (size_t)(k0   + r) * FEAT + f0 + c4);
            As[c4 + 0][r] = av.x; As[c4 + 1][r] = av.y;
            As[c4 + 2][r] = av.z; As[c4 + 3][r] = av.w;
            Us[c4 + 0][r] = uv.x; Us[c4 + 1][r] = uv.y;
            Us[c4 + 2][r] = uv.z; Us[c4 + 3][r] = uv.w;
        }
        __syncthreads();
        #pragma unroll
        for (int kf = 0; kf < BF; ++kf) {
            float4 a0 = *(const float4*)&As[kf][ty * 8];
            float4 a1 = *(const float4*)&As[kf][ty * 8 + 4];
            float4 u0 = *(const float4*)&Us[kf][tx * 8];
            float4 u1 = *(const float4*)&Us[kf][tx * 8 + 4];
            float a[8] = {a0.x, a0.y, a0.z, a0.w, a1.x, a1.y, a1.z, a1.w};
            float u[8] = {u0.x, u0.y, u0.z, u0.w, u1.x, u1.y, u1.z, u1.w};
            #pragma unroll
            for (int i = 0; i < 8; ++i)
                #pragma unroll
                for (int j = 0; j < 8; ++j) acc[i][j] += a[i] * u[j];
        }
        __syncthreads();
    }

    const int b = row0 >> 9;
    float psum[8];
    #pragma unroll
    for (int i = 0; i < 8; ++i) {
        float s = 0.f;
        #pragma unroll
        for (int j = 0; j < 8; ++j) {
            int k = k0 + tx * 8 + j;
            s += tanhf(acc[i][j] + whb[b * KDIM + k]) * wvec[k];
        }
        psum[i] = s;
    }
    #pragma unroll
    for (int off = 8; off > 0; off >>= 1)
        #pragma unroll
        for (int i = 0; i < 8; ++i) psum[i] += __shfl_down(psum[i], off, 16);

    if (tx == 0) {
        int c = blockIdx.y;
        #pragma unroll
        for (int i = 0; i < 8; ++i)
            partial[c * MROWS + row0 + ty * 8 + i] = psum[i];
    }
}

// ---------------------------------------------------------------------------
// k3: energies = sum of 4 partials; softmax over T per batch -> weights
// ---------------------------------------------------------------------------
__global__ __launch_bounds__(512) void k3_softmax(const float* __restrict__ partial,
                                                  float* __restrict__ wout) {
    int b = blockIdx.x;
    int t = threadIdx.x;
    float e = 0.f;
    #pragma unroll
    for (int c = 0; c < 4; ++c) e += partial[c * MROWS + b * TDIM + t];

    __shared__ float sm[512];
    sm[t] = e;
    __syncthreads();
    #pragma unroll
    for (int s = 256; s > 0; s >>= 1) {
        if (t < s) sm[t] = fmaxf(sm[t], sm[t + s]);
        __syncthreads();
    }
    float m = sm[0];
    __syncthreads();
    float ex = __expf(e - m);
    sm[t] = ex;
    __syncthreads();
    #pragma unroll
    for (int s = 256; s > 0; s >>= 1) {
        if (t < s) sm[t] += sm[t + s];
        __syncthreads();
    }
    float inv = 1.f / sm[0];
    wout[b * TDIM + t] = ex * inv;
}

// ---------------------------------------------------------------------------
// k4_partial: T-chunked weighted pooling. grid (FEAT/1024, TCH=16, BATCH) =
// 2048 blocks (~8/CU). Each block: 1024 consecutive f, TCLEN=32 time steps.
// ---------------------------------------------------------------------------
__global__ __launch_bounds__(256) void k4_partial(const float* __restrict__ feats,
                                                  const float* __restrict__ weights,
                                                  float* __restrict__ partial4) {
    int b  = blockIdx.z;
    int t0 = blockIdx.y * TCLEN;
    int f4 = (blockIdx.x * 256 + threadIdx.x) * 4;
    __shared__ float wsm[TCLEN];
    if (threadIdx.x < TCLEN) wsm[threadIdx.x] = weights[b * TDIM + t0 + threadIdx.x];
    __syncthreads();

    const float* fp = feats + (size_t)b * TDIM * FEAT + (size_t)t0 * FEAT + f4;
    float ax = 0.f, ay = 0.f, az = 0.f, aw = 0.f;
    float bx = 0.f, by = 0.f, bz = 0.f, bw = 0.f;
    #pragma unroll 4
    for (int t = 0; t < TCLEN; t += 4) {
        float4 v0 = *(const float4*)(fp + (size_t)(t + 0) * FEAT);
        float4 v1 = *(const float4*)(fp + (size_t)(t + 1) * FEAT);
        float4 v2 = *(const float4*)(fp + (size_t)(t + 2) * FEAT);
        float4 v3 = *(const float4*)(fp + (size_t)(t + 3) * FEAT);
        float w0 = wsm[t], w1 = wsm[t + 1], w2 = wsm[t + 2], w3 = wsm[t + 3];
        ax += v0.x * w0; ay += v0.y * w0; az += v0.z * w0; aw += v0.w * w0;
        bx += v1.x * w1; by += v1.y * w1; bz += v1.z * w1; bw += v1.w * w1;
        ax += v2.x * w2; ay += v2.y * w2; az += v2.z * w2; aw += v2.w * w2;
        bx += v3.x * w3; by += v3.y * w3; bz += v3.z * w3; bw += v3.w * w3;
    }
    float4 o;
    o.x = ax + bx; o.y = ay + by; o.z = az + bz; o.w = aw + bw;
    *(float4*)(partial4 + ((size_t)blockIdx.y * BATCH + b) * FEAT + f4) = o;
}

__global__ __launch_bounds__(256) void k5_reduce(const float* __restrict__ partial4,
                                                 float* __restrict__ out) {
    int i4 = blockIdx.x * 256 + threadIdx.x;  // float4 index into B*FEAT
    float4 s = ((const float4*)partial4)[i4];
    #pragma unroll
    for (int c = 1; c < TCH; ++c) {
        float4 v = ((const float4*)partial4)[(size_t)c * (BATCH * FEAT / 4) + i4];
        s.x += v.x; s.y += v.y; s.z += v.z; s.w += v.w;
    }
    ((float4*)out)[i4] = s;
}

// ---------------------------------------------------------------------------
// k4_direct: single-stage fallback (no ws needed)
// ---------------------------------------------------------------------------
__global__ __launch_bounds__(256) void k4_direct(const float* __restrict__ feats,
                                                 const float* __restrict__ weights,
                                                 float* __restrict__ out) {
    int b = blockIdx.y;
    int f4 = (blockIdx.x * 256 + threadIdx.x) * 4;
    __shared__ float wsm[TDIM];
    wsm[threadIdx.x]       = weights[b * TDIM + threadIdx.x];
    wsm[threadIdx.x + 256] = weights[b * TDIM + 256 + threadIdx.x];
    __syncthreads();

    const float* fp = feats + (size_t)b * TDIM * FEAT + f4;
    float ax = 0.f, ay = 0.f, az = 0.f, aw = 0.f;
    for (int t = 0; t < TDIM; ++t) {
        float4 v = *(const float4*)(fp + (size_t)t * FEAT);
        float w = wsm[t];
        ax += v.x * w; ay += v.y * w; az += v.z * w; aw += v.w * w;
    }
    float4 o = {ax, ay, az, aw};
    *(float4*)(out + (size_t)b * FEAT + f4) = o;
}

// ---------------------------------------------------------------------------
// Launch. d_out: [0, B*FEAT) attn_feats, [B*FEAT, +B*T) weights.
// d_out staging: Whb in weights region (dead after k2); energy partials in
// attn region (dead after k3). d_ws: bf16 feats (128 MB) + bf16 U (2 MB) +
// pooling partials (8 MB). Branch on host-constant ws_size (graph-safe).
// ---------------------------------------------------------------------------
extern "C" void kernel_launch(void* const* d_in, const int* in_sizes, int n_in,
                              void* d_out, int out_size, void* d_ws, size_t ws_size,
                              hipStream_t stream) {
    const float* hidden = (const float*)d_in[0];
    const float* feats  = (const float*)d_in[1];
    const float* W      = (const float*)d_in[2];
    const float* U      = (const float*)d_in[3];
    const float* bias   = (const float*)d_in[4];
    const float* wvec   = (const float*)d_in[5];

    float* out         = (float*)d_out;
    float* attn_out    = out;
    float* weights_out = out + (size_t)BATCH * FEAT;
    float* whb         = weights_out;  // staged (dead after k2)
    float* partial     = attn_out;     // staged (dead after k3)

    const size_t featsN = (size_t)MROWS * FEAT;
    const size_t uN     = (size_t)KDIM * FEAT;
    const size_t bf16Bytes = (featsN + uN) * sizeof(unsigned short);
    const size_t poolBytes = (size_t)TCH * BATCH * FEAT * sizeof(float);
    const bool fast = ws_size >= bf16Bytes + poolBytes;

    k1_whb<<<dim3(KDIM / 4, BATCH), 256, 0, stream>>>(hidden, W, bias, whb);

    if (fast) {
        unsigned short* fBf = (unsigned short*)d_ws;
        unsigned short* uBf = fBf + featsN;
        float* pool4 = (float*)((char*)d_ws + bf16Bytes);
        k_convert2<<<1024, 256, 0, stream>>>(feats, U, fBf, uBf,
                                             (int)(featsN / 4),
                                             (int)((featsN + uN) / 4));
        k2_mfma<<<dim3(MROWS / 256, KDIM / 128), 256, 0, stream>>>(
            fBf, uBf, whb, wvec, partial);
        k3_softmax<<<dim3(BATCH), 512, 0, stream>>>(partial, weights_out);
        k4_partial<<<dim3(FEAT / 1024, TCH, BATCH), 256, 0, stream>>>(
            feats, weights_out, pool4);
        k5_reduce<<<dim3(BATCH * FEAT / 4 / 256), 256, 0, stream>>>(pool4, attn_out);
    } else {
        k2_energy<<<dim3(MROWS / 128, KDIM / 128), 256, 0, stream>>>(
            feats, U, whb, wvec, partial);
        k3_softmax<<<dim3(BATCH), 512, 0, stream>>>(partial, weights_out);
        k4_direct<<<dim3(FEAT / 1024, BATCH), 256, 0, stream>>>(
            feats, weights_out, attn_out);
    }
}

// Round 5
// 499.982 us; speedup vs baseline: 2.3066x; 1.0942x over previous
//
#include <hip/hip_runtime.h>
#include <hip/hip_bf16.h>
#include <math.h>

// Problem constants (from reference)
#define BATCH 64
#define TDIM 512
#define FEAT 2048
#define HID 1024
#define KDIM 512
#define MROWS (BATCH * TDIM)  // 32768 flat feats rows
#define TCH 16                // k4 time-chunks
#define TCLEN (TDIM / TCH)    // 32 t per chunk

#define FEATS4 (MROWS * FEAT / 4)  // 16,777,216 float4/ushort4 units
#define U4 (KDIM * FEAT / 4)       // 262,144

typedef __attribute__((ext_vector_type(8))) short short8;
typedef __attribute__((ext_vector_type(4))) float floatx4;

// global -> LDS direct DMA, 16B per lane; LDS dest is wave-uniform base,
// lane i lands at base + i*16 (per-lane LDS address is NOT honored).
#define GLL16(g, l)                                                     \
    __builtin_amdgcn_global_load_lds(                                   \
        (const __attribute__((address_space(1))) void*)(g),             \
        (__attribute__((address_space(3))) void*)(l), 16, 0, 0)

// ---------------------------------------------------------------------------
// f32 -> bf16 (round-to-nearest-even)
// ---------------------------------------------------------------------------
__device__ __forceinline__ unsigned short f2bf(float x) {
    unsigned int u = __float_as_uint(x);
    u += 0x7FFFu + ((u >> 16) & 1u);
    return (unsigned short)(u >> 16);
}

__device__ __forceinline__ float bf2f(unsigned short s) {
    return __uint_as_float(((unsigned int)s) << 16);
}

// ---------------------------------------------------------------------------
// k0_fused: blocks [0,1792): convert feats f32->bf16 (grid-stride)
//           blocks [1792,2048): convert U f32->bf16
//           blocks [2048,10240): k1 Whb[b,k] = hidden[b]·W[k] + bias[k]
//                                (one wave per output, 4 waves/block)
// ---------------------------------------------------------------------------
__global__ __launch_bounds__(256) void k0_fused(const float* __restrict__ feats,
                                                const float* __restrict__ U,
                                                const float* __restrict__ hidden,
                                                const float* __restrict__ W,
                                                const float* __restrict__ bias,
                                                unsigned short* __restrict__ fB,
                                                unsigned short* __restrict__ uB,
                                                float* __restrict__ whb) {
    int bx = blockIdx.x;
    if (bx < 1792) {
        int stride = 1792 * 256;
        for (int i = bx * 256 + threadIdx.x; i < FEATS4; i += stride) {
            float4 v = ((const float4*)feats)[i];
            ushort4 o;
            o.x = f2bf(v.x); o.y = f2bf(v.y); o.z = f2bf(v.z); o.w = f2bf(v.w);
            ((ushort4*)fB)[i] = o;
        }
    } else if (bx < 2048) {
        int stride = 256 * 256;
        for (int i = (bx - 1792) * 256 + threadIdx.x; i < U4; i += stride) {
            float4 v = ((const float4*)U)[i];
            ushort4 o;
            o.x = f2bf(v.x); o.y = f2bf(v.y); o.z = f2bf(v.z); o.w = f2bf(v.w);
            ((ushort4*)uB)[i] = o;
        }
    } else {
        int bid = bx - 2048;                 // 0..8191
        int b = bid >> 7;                    // 0..63
        int k = (bid & 127) * 4 + (threadIdx.x >> 6);
        int lane = threadIdx.x & 63;
        const float* hrow = hidden + (size_t)b * HID;
        const float* wrow = W + (size_t)k * HID;
        float acc = 0.f;
        #pragma unroll 4
        for (int h = lane; h < HID; h += 64) acc += hrow[h] * wrow[h];
        #pragma unroll
        for (int off = 32; off > 0; off >>= 1) acc += __shfl_down(acc, off, 64);
        if (lane == 0) whb[b * KDIM + k] = acc + bias[k];
    }
}

// ---------------------------------------------------------------------------
// k2_mfma: bf16 MFMA GEMM + fused tanh/dot(w) epilogue.
// Tile M=256 x N=128, BK=64 (32 K-iters: halves barrier-drain count vs BK=32),
// 256 thr = 4 waves (2x2), wave-tile 128x64 (8x4 16x16x32 MFMAs per kk,
// kk in {0,1}). LDS 48 KB -> 2 blocks/CU. Grid (128 m, 4 k0): same-A blocks
// share XCD (flat%8 = m%8) for L2 reuse of A.
// XOR swizzle: LDS 16B-slot s holds global chunk (row=s>>3, q=(s&7)^(row&7));
// read chunk (row, kk*4+quad) at q' = (kk*4+quad)^(col&7) -> all 8 bank-groups
// covered at the 4-lane/group b128 floor (bank-optimal).
// ---------------------------------------------------------------------------
__global__ __launch_bounds__(256, 2) void k2_mfma(const unsigned short* __restrict__ fB,
                                                  const unsigned short* __restrict__ uB,
                                                  const float* __restrict__ whb,
                                                  const float* __restrict__ wvec,
                                                  float* __restrict__ partial) {
    __shared__ unsigned short As[256 * 64];  // 32 KB, unpadded (DMA layout)
    __shared__ unsigned short Bs[128 * 64];  // 16 KB
    __shared__ float sums[2][256];

    const int tid  = threadIdx.x;
    const int wave = tid >> 6;
    const int lane = tid & 63;
    const int row0 = blockIdx.x * 256;
    const int k0   = blockIdx.y * 128;
    const int wm = wave >> 1, wn = wave & 1;
    const int col = lane & 15, quad = lane >> 4;

    // A: 2048 slots of 16B; thread fills slots wave*512 + g*64 + lane, g=0..7.
    // B: 1024 slots; slots wave*256 + g*64 + lane, g=0..3.
    const unsigned short* gA[8];
    unsigned short* lA[8];
    #pragma unroll
    for (int g = 0; g < 8; ++g) {
        int s = wave * 512 + g * 64 + lane;
        int r = s >> 3;
        int q = (s & 7) ^ (r & 7);
        gA[g] = fB + (size_t)(row0 + r) * FEAT + q * 8;
        lA[g] = As + (wave * 512 + g * 64) * 8;  // wave-uniform base
    }
    const unsigned short* gBp[4];
    unsigned short* lB[4];
    #pragma unroll
    for (int g = 0; g < 4; ++g) {
        int s = wave * 256 + g * 64 + lane;
        int r = s >> 3;
        int q = (s & 7) ^ (r & 7);
        gBp[g] = uB + (size_t)(k0 + r) * FEAT + q * 8;
        lB[g] = Bs + (wave * 256 + g * 64) * 8;
    }

    floatx4 acc[8][4];
    #pragma unroll
    for (int i = 0; i < 8; ++i)
        #pragma unroll
        for (int j = 0; j < 4; ++j) acc[i][j] = (floatx4){0.f, 0.f, 0.f, 0.f};

    for (int f0 = 0; f0 < FEAT; f0 += 64) {
        #pragma unroll
        for (int g = 0; g < 8; ++g) { GLL16(gA[g], lA[g]); gA[g] += 64; }
        #pragma unroll
        for (int g = 0; g < 4; ++g) { GLL16(gBp[g], lB[g]); gBp[g] += 64; }
        __syncthreads();

        #pragma unroll
        for (int kk = 0; kk < 2; ++kk) {
            const int sw = ((kk * 4 + quad) ^ (col & 7)) * 8;
            short8 af[8], bf[4];
            #pragma unroll
            for (int i = 0; i < 8; ++i)
                af[i] = *(const short8*)&As[(wm * 128 + i * 16 + col) * 64 + sw];
            #pragma unroll
            for (int j = 0; j < 4; ++j)
                bf[j] = *(const short8*)&Bs[(wn * 64 + j * 16 + col) * 64 + sw];
            #pragma unroll
            for (int i = 0; i < 8; ++i)
                #pragma unroll
                for (int j = 0; j < 4; ++j)
                    acc[i][j] = __builtin_amdgcn_mfma_f32_16x16x32_bf16(
                        af[i], bf[j], acc[i][j], 0, 0, 0);
        }
        __syncthreads();
    }

    // Epilogue. C/D layout: col = lane&15 (n), row = quad*4 + reg (m).
    const int b = row0 >> 9;  // 256-row block stays within one batch (T=512)
    float wk[4], hk[4];
    #pragma unroll
    for (int j = 0; j < 4; ++j) {
        int k = k0 + wn * 64 + j * 16 + col;
        wk[j] = wvec[k];
        hk[j] = whb[b * KDIM + k];
    }
    #pragma unroll
    for (int i = 0; i < 8; ++i) {
        #pragma unroll
        for (int r = 0; r < 4; ++r) {
            float s = 0.f;
            #pragma unroll
            for (int j = 0; j < 4; ++j)
                s += tanhf(acc[i][j][r] + hk[j]) * wk[j];
            #pragma unroll
            for (int off = 8; off > 0; off >>= 1)
                s += __shfl_down(s, off, 16);
            if (col == 0)
                sums[wn][wm * 128 + i * 16 + quad * 4 + r] = s;
        }
    }
    __syncthreads();
    partial[blockIdx.y * MROWS + row0 + tid] = sums[0][tid] + sums[1][tid];
}

// ---------------------------------------------------------------------------
// k2_energy: fp32 fallback (used only if ws_size can't hold bf16 copies)
// ---------------------------------------------------------------------------
#define BM 128
#define BN 128
#define BF 16
#define LDSPAD 4

__global__ __launch_bounds__(256) void k2_energy(const float* __restrict__ feats,
                                                 const float* __restrict__ U,
                                                 const float* __restrict__ whb,
                                                 const float* __restrict__ wvec,
                                                 float* __restrict__ partial) {
    __shared__ __align__(16) float As[BF][BM + LDSPAD];
    __shared__ __align__(16) float Us[BF][BN + LDSPAD];

    const int row0 = blockIdx.x * BM;
    const int k0   = blockIdx.y * BN;
    const int tid  = threadIdx.x;
    const int tx   = tid & 15;
    const int ty   = tid >> 4;

    float acc[8][8];
    #pragma unroll
    for (int i = 0; i < 8; ++i)
        #pragma unroll
        for (int j = 0; j < 8; ++j) acc[i][j] = 0.f;

    for (int f0 = 0; f0 < FEAT; f0 += BF) {
        #pragma unroll
        for (int l = 0; l < 2; ++l) {
            int li = tid + l * 256;
            int r  = li >> 2;
            int c4 = (li & 3) * 4;
            float4 av = *(const float4*)(feats + (size_t)(row0 + r) * FEAT + f0 + c4);
            float4 uv = *(const float4*)(U     + (size_t)(k0   + r) * FEAT + f0 + c4);
            As[c4 + 0][r] = av.x; As[c4 + 1][r] = av.y;
            As[c4 + 2][r] = av.z; As[c4 + 3][r] = av.w;
            Us[c4 + 0][r] = uv.x; Us[c4 + 1][r] = uv.y;
            Us[c4 + 2][r] = uv.z; Us[c4 + 3][r] = uv.w;
        }
        __syncthreads();
        #pragma unroll
        for (int kf = 0; kf < BF; ++kf) {
            float4 a0 = *(const float4*)&As[kf][ty * 8];
            float4 a1 = *(const float4*)&As[kf][ty * 8 + 4];
            float4 u0 = *(const float4*)&Us[kf][tx * 8];
            float4 u1 = *(const float4*)&Us[kf][tx * 8 + 4];
            float a[8] = {a0.x, a0.y, a0.z, a0.w, a1.x, a1.y, a1.z, a1.w};
            float u[8] = {u0.x, u0.y, u0.z, u0.w, u1.x, u1.y, u1.z, u1.w};
            #pragma unroll
            for (int i = 0; i < 8; ++i)
                #pragma unroll
                for (int j = 0; j < 8; ++j) acc[i][j] += a[i] * u[j];
        }
        __syncthreads();
    }

    const int b = row0 >> 9;
    float psum[8];
    #pragma unroll
    for (int i = 0; i < 8; ++i) {
        float s = 0.f;
        #pragma unroll
        for (int j = 0; j < 8; ++j) {
            int k = k0 + tx * 8 + j;
            s += tanhf(acc[i][j] + whb[b * KDIM + k]) * wvec[k];
        }
        psum[i] = s;
    }
    #pragma unroll
    for (int off = 8; off > 0; off >>= 1)
        #pragma unroll
        for (int i = 0; i < 8; ++i) psum[i] += __shfl_down(psum[i], off, 16);

    if (tx == 0) {
        int c = blockIdx.y;
        #pragma unroll
        for (int i = 0; i < 8; ++i)
            partial[c * MROWS + row0 + ty * 8 + i] = psum[i];
    }
}

// ---------------------------------------------------------------------------
// k3: energies = sum of 4 partials; softmax over T per batch -> weights
// ---------------------------------------------------------------------------
__global__ __launch_bounds__(512) void k3_softmax(const float* __restrict__ partial,
                                                  float* __restrict__ wout) {
    int b = blockIdx.x;
    int t = threadIdx.x;
    float e = 0.f;
    #pragma unroll
    for (int c = 0; c < 4; ++c) e += partial[c * MROWS + b * TDIM + t];

    __shared__ float sm[512];
    sm[t] = e;
    __syncthreads();
    #pragma unroll
    for (int s = 256; s > 0; s >>= 1) {
        if (t < s) sm[t] = fmaxf(sm[t], sm[t + s]);
        __syncthreads();
    }
    float m = sm[0];
    __syncthreads();
    float ex = __expf(e - m);
    sm[t] = ex;
    __syncthreads();
    #pragma unroll
    for (int s = 256; s > 0; s >>= 1) {
        if (t < s) sm[t] += sm[t + s];
        __syncthreads();
    }
    float inv = 1.f / sm[0];
    wout[b * TDIM + t] = ex * inv;
}

// ---------------------------------------------------------------------------
// k4_partial_bf: T-chunked weighted pooling over the bf16 feats copy (half the
// traffic of f32). grid (TCH=16, BATCH) = 1024 blocks; block covers all
// FEAT=2048 (8 bf16/thread via 16B loads), TCLEN=32 time steps.
// ---------------------------------------------------------------------------
__global__ __launch_bounds__(256) void k4_partial_bf(const unsigned short* __restrict__ fB,
                                                     const float* __restrict__ weights,
                                                     float* __restrict__ partial4) {
    int b  = blockIdx.y;
    int t0 = blockIdx.x * TCLEN;
    int f8 = threadIdx.x * 8;
    __shared__ float wsm[TCLEN];
    if (threadIdx.x < TCLEN) wsm[threadIdx.x] = weights[b * TDIM + t0 + threadIdx.x];
    __syncthreads();

    const unsigned short* fp = fB + ((size_t)b * TDIM + t0) * FEAT + f8;
    float a[8];
    #pragma unroll
    for (int e = 0; e < 8; ++e) a[e] = 0.f;
    #pragma unroll 4
    for (int t = 0; t < TCLEN; ++t) {
        short8 v = *(const short8*)(fp + (size_t)t * FEAT);
        float w = wsm[t];
        #pragma unroll
        for (int e = 0; e < 8; ++e)
            a[e] += bf2f((unsigned short)v[e]) * w;
    }
    float* op = partial4 + ((size_t)blockIdx.x * BATCH + b) * FEAT + f8;
    float4 o0 = {a[0], a[1], a[2], a[3]};
    float4 o1 = {a[4], a[5], a[6], a[7]};
    *(float4*)op = o0;
    *(float4*)(op + 4) = o1;
}

__global__ __launch_bounds__(256) void k5_reduce(const float* __restrict__ partial4,
                                                 float* __restrict__ out) {
    int i4 = blockIdx.x * 256 + threadIdx.x;  // float4 index into B*FEAT
    float4 s = ((const float4*)partial4)[i4];
    #pragma unroll
    for (int c = 1; c < TCH; ++c) {
        float4 v = ((const float4*)partial4)[(size_t)c * (BATCH * FEAT / 4) + i4];
        s.x += v.x; s.y += v.y; s.z += v.z; s.w += v.w;
    }
    ((float4*)out)[i4] = s;
}

// ---------------------------------------------------------------------------
// Fallback-path kernels (no ws): original k1 + direct f32 pooling
// ---------------------------------------------------------------------------
__global__ __launch_bounds__(256) void k1_whb(const float* __restrict__ hidden,
                                              const float* __restrict__ W,
                                              const float* __restrict__ bias,
                                              float* __restrict__ whb) {
    int b = blockIdx.y;
    int k = blockIdx.x * 4 + (threadIdx.x >> 6);
    int lane = threadIdx.x & 63;
    const float* hrow = hidden + (size_t)b * HID;
    const float* wrow = W + (size_t)k * HID;
    float acc = 0.f;
    #pragma unroll 4
    for (int h = lane; h < HID; h += 64) acc += hrow[h] * wrow[h];
    #pragma unroll
    for (int off = 32; off > 0; off >>= 1) acc += __shfl_down(acc, off, 64);
    if (lane == 0) whb[b * KDIM + k] = acc + bias[k];
}

__global__ __launch_bounds__(256) void k4_direct(const float* __restrict__ feats,
                                                 const float* __restrict__ weights,
                                                 float* __restrict__ out) {
    int b = blockIdx.y;
    int f4 = (blockIdx.x * 256 + threadIdx.x) * 4;
    __shared__ float wsm[TDIM];
    wsm[threadIdx.x]       = weights[b * TDIM + threadIdx.x];
    wsm[threadIdx.x + 256] = weights[b * TDIM + 256 + threadIdx.x];
    __syncthreads();

    const float* fp = feats + (size_t)b * TDIM * FEAT + f4;
    float ax = 0.f, ay = 0.f, az = 0.f, aw = 0.f;
    for (int t = 0; t < TDIM; ++t) {
        float4 v = *(const float4*)(fp + (size_t)t * FEAT);
        float w = wsm[t];
        ax += v.x * w; ay += v.y * w; az += v.z * w; aw += v.w * w;
    }
    float4 o = {ax, ay, az, aw};
    *(float4*)(out + (size_t)b * FEAT + f4) = o;
}

// ---------------------------------------------------------------------------
// Launch. d_out: [0, B*FEAT) attn_feats, [B*FEAT, +B*T) weights.
// d_out staging: Whb in weights region (dead after k2); energy partials in
// attn region (dead after k3). d_ws: bf16 feats (128 MB) + bf16 U (2 MB) +
// pooling partials (8 MB). Branch on host-constant ws_size (graph-safe).
// ---------------------------------------------------------------------------
extern "C" void kernel_launch(void* const* d_in, const int* in_sizes, int n_in,
                              void* d_out, int out_size, void* d_ws, size_t ws_size,
                              hipStream_t stream) {
    const float* hidden = (const float*)d_in[0];
    const float* feats  = (const float*)d_in[1];
    const float* W      = (const float*)d_in[2];
    const float* U      = (const float*)d_in[3];
    const float* bias   = (const float*)d_in[4];
    const float* wvec   = (const float*)d_in[5];

    float* out         = (float*)d_out;
    float* attn_out    = out;
    float* weights_out = out + (size_t)BATCH * FEAT;
    float* whb         = weights_out;  // staged (dead after k2)
    float* partial     = attn_out;     // staged (dead after k3)

    const size_t featsN = (size_t)MROWS * FEAT;
    const size_t uN     = (size_t)KDIM * FEAT;
    const size_t bf16Bytes = (featsN + uN) * sizeof(unsigned short);
    const size_t poolBytes = (size_t)TCH * BATCH * FEAT * sizeof(float);
    const bool fast = ws_size >= bf16Bytes + poolBytes;

    if (fast) {
        unsigned short* fBf = (unsigned short*)d_ws;
        unsigned short* uBf = fBf + featsN;
        float* pool4 = (float*)((char*)d_ws + bf16Bytes);
        k0_fused<<<dim3(10240), 256, 0, stream>>>(feats, U, hidden, W, bias,
                                                  fBf, uBf, whb);
        k2_mfma<<<dim3(MROWS / 256, KDIM / 128), 256, 0, stream>>>(
            fBf, uBf, whb, wvec, partial);
        k3_softmax<<<dim3(BATCH), 512, 0, stream>>>(partial, weights_out);
        k4_partial_bf<<<dim3(TCH, BATCH), 256, 0, stream>>>(
            fBf, weights_out, pool4);
        k5_reduce<<<dim3(BATCH * FEAT / 4 / 256), 256, 0, stream>>>(pool4, attn_out);
    } else {
        k1_whb<<<dim3(KDIM / 4, BATCH), 256, 0, stream>>>(hidden, W, bias, whb);
        k2_energy<<<dim3(MROWS / 128, KDIM / 128), 256, 0, stream>>>(
            feats, U, whb, wvec, partial);
        k3_softmax<<<dim3(BATCH), 512, 0, stream>>>(partial, weights_out);
        k4_direct<<<dim3(FEAT / 1024, BATCH), 256, 0, stream>>>(
            feats, weights_out, attn_out);
    }
}